// Round 12
// baseline (239.457 us; speedup 1.0000x reference)
//
#include <hip/hip_runtime.h>
#include <hip/hip_bf16.h>
#include <cstdint>

#define NPTS 8192
#define DIM  128
#define NA   1024
#define KSEL 64

// ---------------------------------------------------------------------------
// Kernel 1: L1 distance matrix, 8x8 register blocking, NO LDS / NO BARRIERS.
// History (dist_kernel):
//   r2 240VGPR 247us; r4 global_load_lds 213; r5 unroll1 153; r6/r7/r8
//   (reg cap / ping-pong / dbuf+counted-vmcnt) all ~155; r9 conflict-free
//   layout 209 (conflicts 0 -> bank conflicts exonerated); r10 B-from-L2
//   176 (LDS reads halved -> LDS pipe exonerated; regression mechanism:
//   bv compiler-waits share the vmcnt queue with the NEXT tile's A-DMA,
//   forcing the DMA to drain into every compute phase).
//   Invariant r5-r10: dur x VALUBusy = const; real VALU duty ~35% at 155us.
//   Every variant kept the LDS+barrier skeleton (2 barriers/kt, lockstep
//   wave convoys) -> r11 (this): delete the skeleton. Both operands stream
//   from L1/L2 via global_load_dwordx4 into registers; waves fully
//   independent; per kc: 16 VMEM + 512 VALU (1024 cyc) with one-kc-ahead
//   ping-pong (r8's proven codegen shape) -> ~300cyc L2 latency covered 3x.
//   Locality: per-block/kt working set ~32KB; B panels shared by 16 blocks,
//   A rows by 64 blocks -> L2-resident, HBM ~13MB.
// ---------------------------------------------------------------------------
#define BM 128
#define BN 128
#define BK 32

__global__ __launch_bounds__(256)
void dist_kernel(const float* __restrict__ out1, const float* __restrict__ out2,
                 const int* __restrict__ anchor1, const int* __restrict__ anchor2,
                 float* __restrict__ Dmat) {
  const int t = threadIdx.x;
  int bid = blockIdx.x;
  bid = (bid & 7) * 128 + (bid >> 3);   // XCD-chunked swizzle (1024 % 8 == 0)
  const int mt  = bid & 15;             // 16 M-tiles, dir-major
  const int nt  = bid >> 4;             // 64 N-tiles
  const int dir = mt >> 3;
  const int i0  = (mt & 7) * BM;
  const int j0  = nt * BN;

  const float* __restrict__ Abase = dir ? out2 : out1;
  const float* __restrict__ Bbase = dir ? out1 : out2;
  const int* __restrict__ anc     = dir ? anchor2 : anchor1;

  const int ty = t >> 4;     // 0..15 : A rows ty*8..+8
  const int tx = t & 15;     // 0..15 : B rows tx*8..+8

  // A: 8 gathered anchor-row offsets (u32 elements, 8 VGPR).
  uint32_t offA[8];
#pragma unroll
  for (int r = 0; r < 8; ++r)
    offA[r] = (uint32_t)anc[i0 + ty * 8 + r] * DIM;

  // B: one per-thread base; loads fold to base + c*DIM + kc*4 (imm <= 4080B).
  const float* __restrict__ Bp0 = Bbase + (size_t)(j0 + tx * 8) * DIM;

  float acc[8][8];
#pragma unroll
  for (int r = 0; r < 8; ++r)
#pragma unroll
    for (int c = 0; c < 8; ++c) acc[r][c] = 0.f;

#define LOAD_BV(BV, KC)                                                        \
  {                                                                            \
    _Pragma("unroll")                                                          \
    for (int c = 0; c < 8; ++c) BV[c] = *(const float4*)(Bp + c * DIM + (KC) * 4); \
  }

#define LD_A0(KC) (*(const float4*)(Ap0 + (KC) * 4))

// JIT av row loads: row r+1's fragment loaded while row r computes (64 VALU
// lead within the wave; residual latency hidden by other waves — no barriers).
#define COMPUTE_KC(BV, AV0, KC)                                                \
  {                                                                            \
    float4 av = AV0;                                                           \
    _Pragma("unroll")                                                          \
    for (int r = 0; r < 8; ++r) {                                              \
      float4 avn = av;                                                         \
      if (r < 7)                                                               \
        avn = *(const float4*)(Abase + offA[r + 1] + ktoff + (KC) * 4);        \
      _Pragma("unroll")                                                        \
      for (int c = 0; c < 8; ++c) {                                            \
        acc[r][c] += fabsf(av.x - BV[c].x);                                    \
        acc[r][c] += fabsf(av.y - BV[c].y);                                    \
        acc[r][c] += fabsf(av.z - BV[c].z);                                    \
        acc[r][c] += fabsf(av.w - BV[c].w);                                    \
      }                                                                        \
      av = avn;                                                                \
    }                                                                          \
  }

#pragma unroll 1
  for (int kt = 0; kt < 4; ++kt) {
    const uint32_t ktoff = (uint32_t)kt * BK;         // element offset
    const float* __restrict__ Bp  = Bp0 + ktoff;
    const float* __restrict__ Ap0 = Abase + offA[0] + ktoff;

    float4 bvA[8], bvB[8];
    float4 av0A, av0B;
    LOAD_BV(bvA, 0)
    av0A = LD_A0(0);

#pragma unroll 1
    for (int kc2 = 0; kc2 < 4; ++kc2) {
      const int kE = kc2 * 2;
      const int kO = kE + 1;
      LOAD_BV(bvB, kO)                    // prefetch odd kc under even compute
      av0B = LD_A0(kO);
      COMPUTE_KC(bvA, av0A, kE)
      __builtin_amdgcn_sched_barrier(0);  // pin rotation: no rename-hoist
      if (kc2 < 3) {
        LOAD_BV(bvA, kE + 2)              // prefetch next even
        av0A = LD_A0(kE + 2);
      }
      COMPUTE_KC(bvB, av0B, kO)
      __builtin_amdgcn_sched_barrier(0);
    }
  }

#undef LOAD_BV
#undef LD_A0
#undef COMPUTE_KC

  const size_t orow0 = (size_t)(dir * NA + i0 + ty * 8);
#pragma unroll
  for (int r = 0; r < 8; ++r) {
    float4 v0 = make_float4(acc[r][0], acc[r][1], acc[r][2], acc[r][3]);
    float4 v1 = make_float4(acc[r][4], acc[r][5], acc[r][6], acc[r][7]);
    float* dst = Dmat + (orow0 + r) * NPTS + j0 + tx * 8;
    *(float4*)dst       = v0;
    *(float4*)(dst + 4) = v1;
  }
}

// ---------------------------------------------------------------------------
// Kernel 2: per (dir, anchor): exact top-64 via binary search on the uint32
// float key, then hinge-loss terms on the selected set. (passed rounds 0-10)
// ---------------------------------------------------------------------------
__global__ __launch_bounds__(256, 4)
void select_loss_kernel(const float* __restrict__ out1, const float* __restrict__ out2,
                        const float* __restrict__ ot,
                        const int* __restrict__ anchor1, const int* __restrict__ anchor2,
                        const float* __restrict__ Dmat, float* __restrict__ partials) {
  __shared__ float sd[NPTS];
  __shared__ float a_self[DIM];
  __shared__ float terms[KSEL];
  __shared__ int   sel[KSEL];
  __shared__ unsigned wred[4];
  __shared__ float sm_pos;
  __shared__ int sm_cnt, sm_tie;

  const int t   = threadIdx.x;
  const int b   = blockIdx.x;
  const int dir = b >> 10;
  const int i   = b & (NA - 1);

  const int a1i = anchor1[i];
  const int a2i = anchor2[i];
  const int ai_self = dir ? a2i : a1i;
  const float* __restrict__ selfB = dir ? out2 : out1;
  const float* __restrict__ othB  = dir ? out1 : out2;

  const float4* drow = (const float4*)(Dmat + (size_t)b * NPTS);
#pragma unroll
  for (int q = 0; q < 8; ++q) ((float4*)sd)[t + q * 256] = drow[t + q * 256];

  if (t < 32) ((float4*)a_self)[t] = ((const float4*)(selfB + (size_t)ai_self * DIM))[t];

  if (t == 0) { sm_cnt = 0; sm_tie = 0; }

  if (t < 64) {
    const float* r1 = out1 + (size_t)a1i * DIM;
    const float* r2 = out2 + (size_t)a2i * DIM;
    float pz = fabsf(r1[t] - r2[t]) + fabsf(r1[t + 64] - r2[t + 64]);
#pragma unroll
    for (int o = 32; o; o >>= 1) pz += __shfl_down(pz, o);
    if (t == 0) sm_pos = pz;
  }
  __syncthreads();

  unsigned keys[32];
#pragma unroll
  for (int q = 0; q < 32; ++q) keys[q] = __float_as_uint(sd[t + q * 256]);

  unsigned lo = 0u, hi = 0x7F800000u;
  while (lo < hi) {
    unsigned mid = lo + ((hi - lo) >> 1);
    unsigned c = 0;
#pragma unroll
    for (int q = 0; q < 32; ++q) c += (keys[q] <= mid) ? 1u : 0u;
#pragma unroll
    for (int o = 32; o; o >>= 1) c += __shfl_down(c, o);
    if ((t & 63) == 0) wred[t >> 6] = c;
    __syncthreads();
    c = wred[0] + wred[1] + wred[2] + wred[3];
    if (c >= 64u) hi = mid; else lo = mid + 1u;
    __syncthreads();
  }
  const unsigned T = lo;

  {
    unsigned c = 0;
#pragma unroll
    for (int q = 0; q < 32; ++q) c += (keys[q] < T) ? 1u : 0u;
#pragma unroll
    for (int o = 32; o; o >>= 1) c += __shfl_down(c, o);
    if ((t & 63) == 0) wred[t >> 6] = c;
  }
  __syncthreads();
  const int need = 64 - (int)(wred[0] + wred[1] + wred[2] + wred[3]);

#pragma unroll
  for (int q = 0; q < 32; ++q) {
    unsigned k = keys[q];
    bool take = false;
    if (k < T) take = true;
    else if (k == T) take = (atomicAdd(&sm_tie, 1) < need);
    if (take) {
      int s = atomicAdd(&sm_cnt, 1);
      sel[s] = t + q * 256;
    }
  }
  __syncthreads();

  {
    const int s  = t >> 2;
    const int tq = t & 3;
    const int j  = sel[s];
    const float w = dir ? ot[(size_t)j * NPTS + ai_self]
                        : ot[(size_t)ai_self * NPTS + j];
    const float* br = othB + (size_t)j * DIM;
    float dist = 0.f;
#pragma unroll
    for (int d = 0; d < 32; d += 4) {
      float4 bv = *(const float4*)(br + tq * 32 + d);
      dist += fabsf(a_self[tq * 32 + d + 0] - w * bv.x);
      dist += fabsf(a_self[tq * 32 + d + 1] - w * bv.y);
      dist += fabsf(a_self[tq * 32 + d + 2] - w * bv.z);
      dist += fabsf(a_self[tq * 32 + d + 3] - w * bv.w);
    }
    dist += __shfl_xor(dist, 1);
    dist += __shfl_xor(dist, 2);
    if (tq == 0) terms[s] = fmaxf(0.f, sm_pos + 1.0f - dist);
  }
  __syncthreads();

  if (t < 64) {
    float v = terms[t];
#pragma unroll
    for (int o = 32; o; o >>= 1) v += __shfl_down(v, o);
    if (t == 0) partials[b] = v;
  }
}

// ---------------------------------------------------------------------------
// Kernel 3: deterministic reduction of 2048 partials, scale by 1/(A*K).
// ---------------------------------------------------------------------------
__global__ __launch_bounds__(256)
void reduce_kernel(const float* __restrict__ partials, float* __restrict__ outp) {
  __shared__ float ws4[4];
  const int t = threadIdx.x;
  float v = 0.f;
#pragma unroll
  for (int q = 0; q < 8; ++q) v += partials[t + q * 256];
#pragma unroll
  for (int o = 32; o; o >>= 1) v += __shfl_down(v, o);
  if ((t & 63) == 0) ws4[t >> 6] = v;
  __syncthreads();
  if (t == 0) outp[0] = (ws4[0] + ws4[1] + ws4[2] + ws4[3]) * (1.0f / 65536.0f);
}

extern "C" void kernel_launch(void* const* d_in, const int* in_sizes, int n_in,
                              void* d_out, int out_size, void* d_ws, size_t ws_size,
                              hipStream_t stream) {
  (void)in_sizes; (void)n_in; (void)out_size; (void)ws_size;
  const float* out1  = (const float*)d_in[0];
  const float* out2  = (const float*)d_in[1];
  const float* ot    = (const float*)d_in[2];
  const int* anchor1 = (const int*)d_in[3];
  const int* anchor2 = (const int*)d_in[4];

  float* Dmat     = (float*)d_ws;                    // [2048][8192] f32, 64 MiB
  float* partials = Dmat + (size_t)2 * NA * NPTS;    // [2048]

  dist_kernel<<<dim3(16 * 64), dim3(256), 0, stream>>>(out1, out2, anchor1, anchor2, Dmat);
  select_loss_kernel<<<dim3(2 * NA), dim3(256), 0, stream>>>(out1, out2, ot, anchor1, anchor2,
                                                             Dmat, partials);
  reduce_kernel<<<dim3(1), dim3(256), 0, stream>>>(partials, (float*)d_out);
}

// Round 14
// 145.755 us; speedup vs baseline: 1.6429x; 1.6429x over previous
//
#include <hip/hip_runtime.h>
#include <hip/hip_bf16.h>
#include <cstdint>

#define NPTS 8192
#define DIM  128
#define NA   1024
#define KSEL 64

// ---------------------------------------------------------------------------
// Kernel 1: L1 distance matrix via f16 packed max + dot2 (1 VALU instr/elem).
// History: r5/r8 best = 155us. Invariant across r5-r11: dur x VALUBusy ~=
//   12,900 us*% regardless of structure (occupancy, drains, conflicts, LDS
//   pipe, barriers all exonerated by experiment). => VALU issue time is the
//   binding resource (~3cyc/instr effective; m07's own ubench = 66% of
//   nominal). Only lever left: fewer instructions.
// r12/r13: Sum|a-b| = 2*Sum max(a,b) - SumA - SumB. f16: v_pk_max_f16 +
//   v_dot2_f32_f16(m, ones, acc) = 2 instr per 2 elems (was 4). Row sums
//   computed during staging (dot2 on converted halfs, LDS atomic reduce).
//   Dmat stays f32 -> kernels 2/3 untouched; hinge recomputes true f32
//   distances, so f16 only perturbs SELECTION (boundary swaps, ~1e-3 loss).
//   (r13 = r12 with the cvt_pkrtz return type fixed to __fp16-vector.)
// Tiles: dim-major f16 [plane=8dims][row][8 halfs] (2KB/plane, 4 planes/kt);
//   reads: bv 16 lanes x contiguous 16B = conflict-free (r9-verified),
//   stride-16 ownership (row=r*16+ty, col=c*16+tx), scalar f32 epilogue.
// Staging: reg-staged (T14): issue 8 dwordx4 for kt+1 before compute,
//   cvt_pkrtz + ds_write_b128 after; dbuf; one __syncthreads per kt.
// ---------------------------------------------------------------------------
#define BM 128
#define BN 128

typedef __fp16 h2v __attribute__((ext_vector_type(2)));

__device__ __forceinline__ uint32_t pkcvt(float x, float y) {
  h2v h = __builtin_amdgcn_cvt_pkrtz(x, y);
  return __builtin_bit_cast(uint32_t, h);
}
__device__ __forceinline__ void dot2a(float& a, uint32_t m, uint32_t o) {
  asm("v_dot2_f32_f16 %0, %1, %2, %0" : "+v"(a) : "v"(m), "v"(o));
}
__device__ __forceinline__ uint32_t pkmax(uint32_t a, uint32_t b) {
  uint32_t d;
  asm("v_pk_max_f16 %0, %1, %2" : "=v"(d) : "v"(a), "v"(b));
  return d;
}

__global__ __launch_bounds__(256)
void dist_kernel(const float* __restrict__ out1, const float* __restrict__ out2,
                 const int* __restrict__ anchor1, const int* __restrict__ anchor2,
                 float* __restrict__ Dmat) {
  __shared__ alignas(16) char Ah[2][8192];   // [buf][plane*2048 + row*16]
  __shared__ alignas(16) char Bh[2][8192];
  __shared__ float SAs[128], SBs[128];

  const int t = threadIdx.x;
  int bid = blockIdx.x;
  bid = (bid & 7) * 128 + (bid >> 3);   // XCD-chunked swizzle (1024 % 8 == 0)
  const int mt  = bid & 15;
  const int nt  = bid >> 4;
  const int dir = mt >> 3;
  const int i0  = (mt & 7) * BM;
  const int j0  = nt * BN;

  const float* __restrict__ Abase = dir ? out2 : out1;
  const float* __restrict__ Bbase = dir ? out1 : out2;
  const int* __restrict__ anc     = dir ? anchor2 : anchor1;

  // staging: thread t owns row (t&127), planes p0 and p0+2 (p0 = t>>7).
  // LDS dest byte t*16 (+4096 for the second plane) == plane*2048 + row*16.
  const int srow = t & 127;
  const int p0   = t >> 7;
  const int arow = anc[i0 + srow];
  const float* __restrict__ Ag = Abase + (size_t)arow * DIM + p0 * 8;
  const float* __restrict__ Bg = Bbase + (size_t)(j0 + srow) * DIM + p0 * 8;

  const int ty = t >> 4;   // rows r*16+ty
  const int tx = t & 15;   // cols c*16+tx

  float acc[8][8];
#pragma unroll
  for (int r = 0; r < 8; ++r)
#pragma unroll
    for (int c = 0; c < 8; ++c) acc[r][c] = 0.f;

  float sap = 0.f, sbp = 0.f;
  uint32_t ones;
  asm("v_mov_b32 %0, 0x3C003C00" : "=v"(ones));   // (1.0h, 1.0h)

  float4 a0, a1, a2, a3, b0, b1, b2, b3;

#define ISSUE(KT)                                                              \
  a0 = *(const float4*)(Ag + (KT) * 32);                                       \
  a1 = *(const float4*)(Ag + (KT) * 32 + 4);                                   \
  a2 = *(const float4*)(Ag + (KT) * 32 + 16);                                  \
  a3 = *(const float4*)(Ag + (KT) * 32 + 20);                                  \
  b0 = *(const float4*)(Bg + (KT) * 32);                                       \
  b1 = *(const float4*)(Bg + (KT) * 32 + 4);                                   \
  b2 = *(const float4*)(Bg + (KT) * 32 + 16);                                  \
  b3 = *(const float4*)(Bg + (KT) * 32 + 20);

#define CVTW(BUF)                                                              \
  {                                                                            \
    uint4 u;                                                                   \
    u.x = pkcvt(a0.x, a0.y); u.y = pkcvt(a0.z, a0.w);                          \
    u.z = pkcvt(a1.x, a1.y); u.w = pkcvt(a1.z, a1.w);                          \
    dot2a(sap, u.x, ones); dot2a(sap, u.y, ones);                              \
    dot2a(sap, u.z, ones); dot2a(sap, u.w, ones);                              \
    *(uint4*)(&Ah[BUF][t * 16]) = u;                                           \
    u.x = pkcvt(a2.x, a2.y); u.y = pkcvt(a2.z, a2.w);                          \
    u.z = pkcvt(a3.x, a3.y); u.w = pkcvt(a3.z, a3.w);                          \
    dot2a(sap, u.x, ones); dot2a(sap, u.y, ones);                              \
    dot2a(sap, u.z, ones); dot2a(sap, u.w, ones);                              \
    *(uint4*)(&Ah[BUF][t * 16 + 4096]) = u;                                    \
    u.x = pkcvt(b0.x, b0.y); u.y = pkcvt(b0.z, b0.w);                          \
    u.z = pkcvt(b1.x, b1.y); u.w = pkcvt(b1.z, b1.w);                          \
    dot2a(sbp, u.x, ones); dot2a(sbp, u.y, ones);                              \
    dot2a(sbp, u.z, ones); dot2a(sbp, u.w, ones);                              \
    *(uint4*)(&Bh[BUF][t * 16]) = u;                                           \
    u.x = pkcvt(b2.x, b2.y); u.y = pkcvt(b2.z, b2.w);                          \
    u.z = pkcvt(b3.x, b3.y); u.w = pkcvt(b3.z, b3.w);                          \
    dot2a(sbp, u.x, ones); dot2a(sbp, u.y, ones);                              \
    dot2a(sbp, u.z, ones); dot2a(sbp, u.w, ones);                              \
    *(uint4*)(&Bh[BUF][t * 16 + 4096]) = u;                                    \
  }

  // prologue: stage tile 0 into buffer 0; init rowsum arrays
  ISSUE(0)
  CVTW(0)
  if (t < 128) { SAs[t] = 0.f; SBs[t] = 0.f; }
  __syncthreads();

#pragma unroll 1
  for (int kt = 0; kt < 4; ++kt) {
    const int buf = kt & 1;
    if (kt < 3) { ISSUE(kt + 1) }          // loads land under compute
    __builtin_amdgcn_sched_barrier(0);

    const char* const Ab = &Ah[buf][0] + ty * 16;
    const char* const Bb = &Bh[buf][0] + tx * 16;

#pragma unroll 1
    for (int kc = 0; kc < 4; ++kc) {        // kc = plane of 8 dims
      uint4 bv[8];
#pragma unroll
      for (int c = 0; c < 8; ++c)
        bv[c] = *(const uint4*)(Bb + kc * 2048 + c * 256);
      uint4 av = *(const uint4*)(Ab + kc * 2048);
#pragma unroll
      for (int r = 0; r < 8; ++r) {
        uint4 avn = av;
        if (r < 7) avn = *(const uint4*)(Ab + kc * 2048 + (r + 1) * 256);
#pragma unroll
        for (int c = 0; c < 8; ++c) {
          dot2a(acc[r][c], pkmax(av.x, bv[c].x), ones);
          dot2a(acc[r][c], pkmax(av.y, bv[c].y), ones);
          dot2a(acc[r][c], pkmax(av.z, bv[c].z), ones);
          dot2a(acc[r][c], pkmax(av.w, bv[c].w), ones);
        }
        av = avn;
      }
    }

    __builtin_amdgcn_sched_barrier(0);
    if (kt < 3) { CVTW(buf ^ 1) }
    __syncthreads();
  }

#undef ISSUE
#undef CVTW

  // rowsum reduce: threads t and t^128 each hold half the dims of row t&127
  atomicAdd(&SAs[srow], sap);
  atomicAdd(&SBs[srow], sbp);
  __syncthreads();

  float sa[8], sb[8];
#pragma unroll
  for (int r = 0; r < 8; ++r) sa[r] = SAs[r * 16 + ty];
#pragma unroll
  for (int c = 0; c < 8; ++c) sb[c] = SBs[c * 16 + tx];

#pragma unroll
  for (int r = 0; r < 8; ++r) {
    float* dst = Dmat + (size_t)(dir * NA + i0 + r * 16 + ty) * NPTS + j0 + tx;
#pragma unroll
    for (int c = 0; c < 8; ++c)
      dst[c * 16] = 2.f * acc[r][c] - sa[r] - sb[c];
  }
}

// ---------------------------------------------------------------------------
// Kernel 2: per (dir, anchor): exact top-64 via binary search on the uint32
// float key, then hinge-loss terms on the selected set. (passed rounds 0-11)
// ---------------------------------------------------------------------------
__global__ __launch_bounds__(256, 4)
void select_loss_kernel(const float* __restrict__ out1, const float* __restrict__ out2,
                        const float* __restrict__ ot,
                        const int* __restrict__ anchor1, const int* __restrict__ anchor2,
                        const float* __restrict__ Dmat, float* __restrict__ partials) {
  __shared__ float sd[NPTS];
  __shared__ float a_self[DIM];
  __shared__ float terms[KSEL];
  __shared__ int   sel[KSEL];
  __shared__ unsigned wred[4];
  __shared__ float sm_pos;
  __shared__ int sm_cnt, sm_tie;

  const int t   = threadIdx.x;
  const int b   = blockIdx.x;
  const int dir = b >> 10;
  const int i   = b & (NA - 1);

  const int a1i = anchor1[i];
  const int a2i = anchor2[i];
  const int ai_self = dir ? a2i : a1i;
  const float* __restrict__ selfB = dir ? out2 : out1;
  const float* __restrict__ othB  = dir ? out1 : out2;

  const float4* drow = (const float4*)(Dmat + (size_t)b * NPTS);
#pragma unroll
  for (int q = 0; q < 8; ++q) ((float4*)sd)[t + q * 256] = drow[t + q * 256];

  if (t < 32) ((float4*)a_self)[t] = ((const float4*)(selfB + (size_t)ai_self * DIM))[t];

  if (t == 0) { sm_cnt = 0; sm_tie = 0; }

  if (t < 64) {
    const float* r1 = out1 + (size_t)a1i * DIM;
    const float* r2 = out2 + (size_t)a2i * DIM;
    float pz = fabsf(r1[t] - r2[t]) + fabsf(r1[t + 64] - r2[t + 64]);
#pragma unroll
    for (int o = 32; o; o >>= 1) pz += __shfl_down(pz, o);
    if (t == 0) sm_pos = pz;
  }
  __syncthreads();

  unsigned keys[32];
#pragma unroll
  for (int q = 0; q < 32; ++q) keys[q] = __float_as_uint(sd[t + q * 256]);

  unsigned lo = 0u, hi = 0x7F800000u;
  while (lo < hi) {
    unsigned mid = lo + ((hi - lo) >> 1);
    unsigned c = 0;
#pragma unroll
    for (int q = 0; q < 32; ++q) c += (keys[q] <= mid) ? 1u : 0u;
#pragma unroll
    for (int o = 32; o; o >>= 1) c += __shfl_down(c, o);
    if ((t & 63) == 0) wred[t >> 6] = c;
    __syncthreads();
    c = wred[0] + wred[1] + wred[2] + wred[3];
    if (c >= 64u) hi = mid; else lo = mid + 1u;
    __syncthreads();
  }
  const unsigned T = lo;

  {
    unsigned c = 0;
#pragma unroll
    for (int q = 0; q < 32; ++q) c += (keys[q] < T) ? 1u : 0u;
#pragma unroll
    for (int o = 32; o; o >>= 1) c += __shfl_down(c, o);
    if ((t & 63) == 0) wred[t >> 6] = c;
  }
  __syncthreads();
  const int need = 64 - (int)(wred[0] + wred[1] + wred[2] + wred[3]);

#pragma unroll
  for (int q = 0; q < 32; ++q) {
    unsigned k = keys[q];
    bool take = false;
    if (k < T) take = true;
    else if (k == T) take = (atomicAdd(&sm_tie, 1) < need);
    if (take) {
      int s = atomicAdd(&sm_cnt, 1);
      sel[s] = t + q * 256;
    }
  }
  __syncthreads();

  {
    const int s  = t >> 2;
    const int tq = t & 3;
    const int j  = sel[s];
    const float w = dir ? ot[(size_t)j * NPTS + ai_self]
                        : ot[(size_t)ai_self * NPTS + j];
    const float* br = othB + (size_t)j * DIM;
    float dist = 0.f;
#pragma unroll
    for (int d = 0; d < 32; d += 4) {
      float4 bv = *(const float4*)(br + tq * 32 + d);
      dist += fabsf(a_self[tq * 32 + d + 0] - w * bv.x);
      dist += fabsf(a_self[tq * 32 + d + 1] - w * bv.y);
      dist += fabsf(a_self[tq * 32 + d + 2] - w * bv.z);
      dist += fabsf(a_self[tq * 32 + d + 3] - w * bv.w);
    }
    dist += __shfl_xor(dist, 1);
    dist += __shfl_xor(dist, 2);
    if (tq == 0) terms[s] = fmaxf(0.f, sm_pos + 1.0f - dist);
  }
  __syncthreads();

  if (t < 64) {
    float v = terms[t];
#pragma unroll
    for (int o = 32; o; o >>= 1) v += __shfl_down(v, o);
    if (t == 0) partials[b] = v;
  }
}

// ---------------------------------------------------------------------------
// Kernel 3: deterministic reduction of 2048 partials, scale by 1/(A*K).
// ---------------------------------------------------------------------------
__global__ __launch_bounds__(256)
void reduce_kernel(const float* __restrict__ partials, float* __restrict__ outp) {
  __shared__ float ws4[4];
  const int t = threadIdx.x;
  float v = 0.f;
#pragma unroll
  for (int q = 0; q < 8; ++q) v += partials[t + q * 256];
#pragma unroll
  for (int o = 32; o; o >>= 1) v += __shfl_down(v, o);
  if ((t & 63) == 0) ws4[t >> 6] = v;
  __syncthreads();
  if (t == 0) outp[0] = (ws4[0] + ws4[1] + ws4[2] + ws4[3]) * (1.0f / 65536.0f);
}

extern "C" void kernel_launch(void* const* d_in, const int* in_sizes, int n_in,
                              void* d_out, int out_size, void* d_ws, size_t ws_size,
                              hipStream_t stream) {
  (void)in_sizes; (void)n_in; (void)out_size; (void)ws_size;
  const float* out1  = (const float*)d_in[0];
  const float* out2  = (const float*)d_in[1];
  const float* ot    = (const float*)d_in[2];
  const int* anchor1 = (const int*)d_in[3];
  const int* anchor2 = (const int*)d_in[4];

  float* Dmat     = (float*)d_ws;                    // [2048][8192] f32, 64 MiB
  float* partials = Dmat + (size_t)2 * NA * NPTS;    // [2048]

  dist_kernel<<<dim3(16 * 64), dim3(256), 0, stream>>>(out1, out2, anchor1, anchor2, Dmat);
  select_loss_kernel<<<dim3(2 * NA), dim3(256), 0, stream>>>(out1, out2, ot, anchor1, anchor2,
                                                             Dmat, partials);
  reduce_kernel<<<dim3(1), dim3(256), 0, stream>>>(partials, (float*)d_out);
}

// Round 15
// 120.392 us; speedup vs baseline: 1.9890x; 1.2107x over previous
//
#include <hip/hip_runtime.h>
#include <hip/hip_bf16.h>
#include <cstdint>

#define NPTS 8192
#define DIM  128
#define NA   1024
#define KSEL 64

#define AS1 __attribute__((address_space(1)))
#define AS3 __attribute__((address_space(3)))

typedef unsigned short ushort_t;
typedef __fp16 h2v __attribute__((ext_vector_type(2)));

__device__ __forceinline__ uint32_t pkcvt(float x, float y) {
  h2v h = __builtin_amdgcn_cvt_pkrtz(x, y);
  return __builtin_bit_cast(uint32_t, h);
}
__device__ __forceinline__ void dot2a(float& a, uint32_t m, uint32_t o) {
  asm("v_dot2_f32_f16 %0, %1, %2, %0" : "+v"(a) : "v"(m), "v"(o));
}
__device__ __forceinline__ uint32_t pkmax(uint32_t a, uint32_t b) {
  uint32_t d;
  asm("v_pk_max_f16 %0, %1, %2" : "=v"(d) : "v"(a), "v"(b));
  return d;
}

// ---------------------------------------------------------------------------
// Kernel 0: f32 -> f16 copies of out1/out2 + per-row sums of the f16 values.
// 8 rows per block; lane l handles dims l*4..l*4+3 of row t>>5.
// ---------------------------------------------------------------------------
__global__ __launch_bounds__(256)
void convert_kernel(const float* __restrict__ out1, const float* __restrict__ out2,
                    ushort_t* __restrict__ h1, ushort_t* __restrict__ h2,
                    float* __restrict__ S1, float* __restrict__ S2) {
  const int t    = threadIdx.x;
  const int side = blockIdx.x >> 10;
  const int row  = (blockIdx.x & 1023) * 8 + (t >> 5);
  const int lane = t & 31;

  uint32_t ones;
  asm("v_mov_b32 %0, 0x3C003C00" : "=v"(ones));

  const float* src = (side ? out2 : out1) + (size_t)row * DIM + lane * 4;
  ushort_t* dsth   = (side ? h2 : h1) + (size_t)row * DIM + lane * 4;
  float4 v = *(const float4*)src;
  uint2 u;
  u.x = pkcvt(v.x, v.y);
  u.y = pkcvt(v.z, v.w);
  *(uint2*)dsth = u;

  float s = 0.f;
  dot2a(s, u.x, ones);
  dot2a(s, u.y, ones);
#pragma unroll
  for (int o = 16; o; o >>= 1) s += __shfl_xor(s, o);   // within 32-lane group
  if (lane == 0) (side ? S2 : S1)[row] = s;
}

// ---------------------------------------------------------------------------
// Kernel 1: L1 distance matrix, f16 pkmax+dot2 (1 VALU instr/elem), f16 out.
// History: VALU-issue count proven to be the binding resource (r5-r13:
//   dur x VALUBusy invariant; f16 halving r13 = 155 -> ~100us dist).
// r14: conversion hoisted to convert_kernel -> dist stages f16 tiles via
//   global_load_lds DMA (r8's verified dbuf + raw-barrier + counted-vmcnt
//   skeleton, 4 loads/stage -> vmcnt(4)); no staging VALU, no held staging
//   regs (~125 VGPR -> 3 waves/SIMD). Row sums read precomputed. Dmat f16
//   (halves D traffic; select's keys become u16 -> 15-iter search).
// Tiles: dim-major [plane=8dims][row] f16, 2KB/plane, 4 planes/kt, 8KB/buf;
//   bv reads 16 lanes x contiguous 16B (conflict-free, r9-verified).
// ---------------------------------------------------------------------------
#define BM 128
#define BN 128

__global__ __launch_bounds__(256)
void dist_kernel(const ushort_t* __restrict__ h1, const ushort_t* __restrict__ h2,
                 const int* __restrict__ anchor1, const int* __restrict__ anchor2,
                 const float* __restrict__ S1, const float* __restrict__ S2,
                 ushort_t* __restrict__ Dmat) {
  __shared__ alignas(16) char Ah[2][8192];   // [buf][plane*2048 + row*16]
  __shared__ alignas(16) char Bh[2][8192];

  const int t = threadIdx.x;
  int bid = blockIdx.x;
  bid = (bid & 7) * 128 + (bid >> 3);   // XCD-chunked swizzle (1024 % 8 == 0)
  const int mt  = bid & 15;
  const int nt  = bid >> 4;
  const int dir = mt >> 3;
  const int i0  = (mt & 7) * BM;
  const int j0  = nt * BN;

  const ushort_t* __restrict__ Ah16 = dir ? h2 : h1;
  const ushort_t* __restrict__ Bh16 = dir ? h1 : h2;
  const float* __restrict__ SA = dir ? S2 : S1;
  const float* __restrict__ SB = dir ? S1 : S2;
  const int* __restrict__ anc  = dir ? anchor2 : anchor1;

  // staging: thread t stages row (t&127), planes p0+2q (p0=t>>7, q=0,1).
  // LDS dest byte t*16 + q*4096 == plane*2048 + row*16 (lane-linear).
  const int srow = t & 127;
  const int p0   = t >> 7;
  const int arow = anc[i0 + srow];
  uint32_t offA[2], offB[2];
#pragma unroll
  for (int q = 0; q < 2; ++q) {
    const int plane = p0 + 2 * q;
    offA[q] = (uint32_t)arow * DIM + plane * 8;           // halfs
    offB[q] = (uint32_t)(j0 + srow) * DIM + plane * 8;
  }

  const int ty = t >> 4;   // rows r*16+ty
  const int tx = t & 15;   // cols c*16+tx

  float acc[8][8];
#pragma unroll
  for (int r = 0; r < 8; ++r)
#pragma unroll
    for (int c = 0; c < 8; ++c) acc[r][c] = 0.f;

  uint32_t ones;
  asm("v_mov_b32 %0, 0x3C003C00" : "=v"(ones));

#define STAGE(BUF, KT)                                                         \
  {                                                                            \
    _Pragma("unroll")                                                          \
    for (int q = 0; q < 2; ++q) {                                              \
      __builtin_amdgcn_global_load_lds(                                        \
          (const AS1 uint32_t*)(Ah16 + offA[q] + (KT) * 32),                   \
          (AS3 uint32_t*)(&Ah[BUF][t * 16 + q * 4096]), 16, 0, 0);             \
      __builtin_amdgcn_global_load_lds(                                        \
          (const AS1 uint32_t*)(Bh16 + offB[q] + (KT) * 32),                   \
          (AS3 uint32_t*)(&Bh[BUF][t * 16 + q * 4096]), 16, 0, 0);             \
    }                                                                          \
  }

  STAGE(0, 0)

#pragma unroll 1
  for (int kt = 0; kt < 4; ++kt) {
    __builtin_amdgcn_s_barrier();        // all waves done with other buf
    if (kt < 3) {
      STAGE((kt + 1) & 1, kt + 1)
      asm volatile("s_waitcnt vmcnt(4)" ::: "memory");   // prev batch landed
    } else {
      asm volatile("s_waitcnt vmcnt(0)" ::: "memory");
    }
    __builtin_amdgcn_s_barrier();        // buf[kt&1] resident for all
    __builtin_amdgcn_sched_barrier(0);

    const char* const Ab = &Ah[kt & 1][0] + ty * 16;
    const char* const Bb = &Bh[kt & 1][0] + tx * 16;

#pragma unroll 1
    for (int kc = 0; kc < 4; ++kc) {     // plane of 8 dims
      uint4 bv[8];
#pragma unroll
      for (int c = 0; c < 8; ++c)
        bv[c] = *(const uint4*)(Bb + kc * 2048 + c * 256);
      uint4 av = *(const uint4*)(Ab + kc * 2048);
#pragma unroll
      for (int r = 0; r < 8; ++r) {
        uint4 avn = av;
        if (r < 7) avn = *(const uint4*)(Ab + kc * 2048 + (r + 1) * 256);
#pragma unroll
        for (int c = 0; c < 8; ++c) {
          dot2a(acc[r][c], pkmax(av.x, bv[c].x), ones);
          dot2a(acc[r][c], pkmax(av.y, bv[c].y), ones);
          dot2a(acc[r][c], pkmax(av.z, bv[c].z), ones);
          dot2a(acc[r][c], pkmax(av.w, bv[c].w), ones);
        }
        av = avn;
      }
    }
  }

#undef STAGE

  float sa[8], sb[8];
#pragma unroll
  for (int r = 0; r < 8; ++r) sa[r] = SA[anc[i0 + r * 16 + ty]];
#pragma unroll
  for (int c = 0; c < 8; ++c) sb[c] = SB[j0 + c * 16 + tx];

#pragma unroll
  for (int r = 0; r < 8; ++r) {
    ushort_t* dst = Dmat + (size_t)(dir * NA + i0 + r * 16 + ty) * NPTS + j0 + tx;
#pragma unroll
    for (int c = 0; c < 8; ++c) {
      float d = 2.f * acc[r][c] - sa[r] - sb[c];
      dst[c * 16] = (ushort_t)pkcvt(d, 0.f);
    }
  }
}

// ---------------------------------------------------------------------------
// Kernel 2: per (dir, anchor): exact top-64 via binary search on the u16
// f16-key (15 iters), then hinge on exact f32 recomputed distances.
// ---------------------------------------------------------------------------
__global__ __launch_bounds__(256, 4)
void select_loss_kernel(const float* __restrict__ out1, const float* __restrict__ out2,
                        const float* __restrict__ ot,
                        const int* __restrict__ anchor1, const int* __restrict__ anchor2,
                        const ushort_t* __restrict__ Dmat, float* __restrict__ partials) {
  __shared__ ushort_t sdh[NPTS];      // 16 KiB f16 distance row
  __shared__ float a_self[DIM];
  __shared__ float terms[KSEL];
  __shared__ int   sel[KSEL];
  __shared__ unsigned wred[4];
  __shared__ float sm_pos;
  __shared__ int sm_cnt, sm_tie;

  const int t   = threadIdx.x;
  const int b   = blockIdx.x;
  const int dir = b >> 10;
  const int i   = b & (NA - 1);

  const int a1i = anchor1[i];
  const int a2i = anchor2[i];
  const int ai_self = dir ? a2i : a1i;
  const float* __restrict__ selfB = dir ? out2 : out1;
  const float* __restrict__ othB  = dir ? out1 : out2;

  const uint4* drow = (const uint4*)(Dmat + (size_t)b * NPTS);
#pragma unroll
  for (int q = 0; q < 4; ++q) ((uint4*)sdh)[t + q * 256] = drow[t + q * 256];

  if (t < 32) ((float4*)a_self)[t] = ((const float4*)(selfB + (size_t)ai_self * DIM))[t];

  if (t == 0) { sm_cnt = 0; sm_tie = 0; }

  if (t < 64) {
    const float* r1 = out1 + (size_t)a1i * DIM;
    const float* r2 = out2 + (size_t)a2i * DIM;
    float pz = fabsf(r1[t] - r2[t]) + fabsf(r1[t + 64] - r2[t + 64]);
#pragma unroll
    for (int o = 32; o; o >>= 1) pz += __shfl_down(pz, o);
    if (t == 0) sm_pos = pz;
  }
  __syncthreads();

  unsigned keys[32];
#pragma unroll
  for (int q = 0; q < 32; ++q) keys[q] = sdh[t + q * 256];

  unsigned lo = 0u, hi = 0x7C00u;      // f16 +inf key; 15 iterations
  while (lo < hi) {
    unsigned mid = lo + ((hi - lo) >> 1);
    unsigned c = 0;
#pragma unroll
    for (int q = 0; q < 32; ++q) c += (keys[q] <= mid) ? 1u : 0u;
#pragma unroll
    for (int o = 32; o; o >>= 1) c += __shfl_down(c, o);
    if ((t & 63) == 0) wred[t >> 6] = c;
    __syncthreads();
    c = wred[0] + wred[1] + wred[2] + wred[3];
    if (c >= 64u) hi = mid; else lo = mid + 1u;
    __syncthreads();
  }
  const unsigned T = lo;

  {
    unsigned c = 0;
#pragma unroll
    for (int q = 0; q < 32; ++q) c += (keys[q] < T) ? 1u : 0u;
#pragma unroll
    for (int o = 32; o; o >>= 1) c += __shfl_down(c, o);
    if ((t & 63) == 0) wred[t >> 6] = c;
  }
  __syncthreads();
  const int need = 64 - (int)(wred[0] + wred[1] + wred[2] + wred[3]);

#pragma unroll
  for (int q = 0; q < 32; ++q) {
    unsigned k = keys[q];
    bool take = false;
    if (k < T) take = true;
    else if (k == T) take = (atomicAdd(&sm_tie, 1) < need);
    if (take) {
      int s = atomicAdd(&sm_cnt, 1);
      sel[s] = t + q * 256;
    }
  }
  __syncthreads();

  {
    const int s  = t >> 2;
    const int tq = t & 3;
    const int j  = sel[s];
    const float w = dir ? ot[(size_t)j * NPTS + ai_self]
                        : ot[(size_t)ai_self * NPTS + j];
    const float* br = othB + (size_t)j * DIM;
    float dist = 0.f;
#pragma unroll
    for (int d = 0; d < 32; d += 4) {
      float4 bv = *(const float4*)(br + tq * 32 + d);
      dist += fabsf(a_self[tq * 32 + d + 0] - w * bv.x);
      dist += fabsf(a_self[tq * 32 + d + 1] - w * bv.y);
      dist += fabsf(a_self[tq * 32 + d + 2] - w * bv.z);
      dist += fabsf(a_self[tq * 32 + d + 3] - w * bv.w);
    }
    dist += __shfl_xor(dist, 1);
    dist += __shfl_xor(dist, 2);
    if (tq == 0) terms[s] = fmaxf(0.f, sm_pos + 1.0f - dist);
  }
  __syncthreads();

  if (t < 64) {
    float v = terms[t];
#pragma unroll
    for (int o = 32; o; o >>= 1) v += __shfl_down(v, o);
    if (t == 0) partials[b] = v;
  }
}

// ---------------------------------------------------------------------------
// Kernel 3: deterministic reduction of 2048 partials, scale by 1/(A*K).
// ---------------------------------------------------------------------------
__global__ __launch_bounds__(256)
void reduce_kernel(const float* __restrict__ partials, float* __restrict__ outp) {
  __shared__ float ws4[4];
  const int t = threadIdx.x;
  float v = 0.f;
#pragma unroll
  for (int q = 0; q < 8; ++q) v += partials[t + q * 256];
#pragma unroll
  for (int o = 32; o; o >>= 1) v += __shfl_down(v, o);
  if ((t & 63) == 0) ws4[t >> 6] = v;
  __syncthreads();
  if (t == 0) outp[0] = (ws4[0] + ws4[1] + ws4[2] + ws4[3]) * (1.0f / 65536.0f);
}

extern "C" void kernel_launch(void* const* d_in, const int* in_sizes, int n_in,
                              void* d_out, int out_size, void* d_ws, size_t ws_size,
                              hipStream_t stream) {
  (void)in_sizes; (void)n_in; (void)out_size; (void)ws_size;
  const float* out1  = (const float*)d_in[0];
  const float* out2  = (const float*)d_in[1];
  const float* ot    = (const float*)d_in[2];
  const int* anchor1 = (const int*)d_in[3];
  const int* anchor2 = (const int*)d_in[4];

  // ws layout (bytes):
  //   Dmat f16 [2048][8192]            @ 0         (32 MiB)
  //   h1 f16 [8192][128]               @ 33554432  (2 MiB)
  //   h2 f16 [8192][128]               @ 35651584  (2 MiB)
  //   S1 f32 [8192]                    @ 37748736  (32 KiB)
  //   S2 f32 [8192]                    @ 37781504  (32 KiB)
  //   partials f32 [2048]              @ 37814272  (8 KiB)
  char* ws = (char*)d_ws;
  ushort_t* Dmat  = (ushort_t*)ws;
  ushort_t* h1    = (ushort_t*)(ws + 33554432);
  ushort_t* h2    = (ushort_t*)(ws + 35651584);
  float* S1       = (float*)(ws + 37748736);
  float* S2       = (float*)(ws + 37781504);
  float* partials = (float*)(ws + 37814272);

  convert_kernel<<<dim3(2048), dim3(256), 0, stream>>>(out1, out2, h1, h2, S1, S2);
  dist_kernel<<<dim3(16 * 64), dim3(256), 0, stream>>>(h1, h2, anchor1, anchor2, S1, S2, Dmat);
  select_loss_kernel<<<dim3(2 * NA), dim3(256), 0, stream>>>(out1, out2, ot, anchor1, anchor2,
                                                             Dmat, partials);
  reduce_kernel<<<dim3(1), dim3(256), 0, stream>>>(partials, (float*)d_out);
}

// Round 16
// 110.114 us; speedup vs baseline: 2.1746x; 1.0933x over previous
//
#include <hip/hip_runtime.h>
#include <hip/hip_bf16.h>
#include <cstdint>

#define NPTS 8192
#define DIM  128
#define NA   1024
#define KSEL 64

#define AS1 __attribute__((address_space(1)))
#define AS3 __attribute__((address_space(3)))

typedef unsigned short ushort_t;
typedef __fp16 h2v __attribute__((ext_vector_type(2)));

__device__ __forceinline__ uint32_t pkcvt(float x, float y) {
  h2v h = __builtin_amdgcn_cvt_pkrtz(x, y);
  return __builtin_bit_cast(uint32_t, h);
}
__device__ __forceinline__ void dot2a(float& a, uint32_t m, uint32_t o) {
  asm("v_dot2_f32_f16 %0, %1, %2, %0" : "+v"(a) : "v"(m), "v"(o));
}
__device__ __forceinline__ uint32_t pkmax(uint32_t a, uint32_t b) {
  uint32_t d;
  asm("v_pk_max_f16 %0, %1, %2" : "=v"(d) : "v"(a), "v"(b));
  return d;
}

// ---------------------------------------------------------------------------
// Kernel 0: f32 -> f16 copies of out1/out2 + per-row sums of the f16 values.
// ---------------------------------------------------------------------------
__global__ __launch_bounds__(256)
void convert_kernel(const float* __restrict__ out1, const float* __restrict__ out2,
                    ushort_t* __restrict__ h1, ushort_t* __restrict__ h2,
                    float* __restrict__ S1, float* __restrict__ S2) {
  const int t    = threadIdx.x;
  const int side = blockIdx.x >> 10;
  const int row  = (blockIdx.x & 1023) * 8 + (t >> 5);
  const int lane = t & 31;

  uint32_t ones;
  asm("v_mov_b32 %0, 0x3C003C00" : "=v"(ones));

  const float* src = (side ? out2 : out1) + (size_t)row * DIM + lane * 4;
  ushort_t* dsth   = (side ? h2 : h1) + (size_t)row * DIM + lane * 4;
  float4 v = *(const float4*)src;
  uint2 u;
  u.x = pkcvt(v.x, v.y);
  u.y = pkcvt(v.z, v.w);
  *(uint2*)dsth = u;

  float s = 0.f;
  dot2a(s, u.x, ones);
  dot2a(s, u.y, ones);
#pragma unroll
  for (int o = 16; o; o >>= 1) s += __shfl_xor(s, o);
  if (lane == 0) (side ? S2 : S1)[row] = s;
}

// ---------------------------------------------------------------------------
// Kernel 1: L1 distance matrix, f16 pkmax+dot2 (1 VALU instr/elem = the
// packed-ISA minimum), f16 output. FROZEN from r14 (verified, ~2x gain).
// History: r5-r13 established VALU-issue count as the binding resource
// (dur x VALUBusy invariant across 7 structural variants); f16 halving
// delivered r13 145.8 / r14 120.4 total.
// ---------------------------------------------------------------------------
#define BM 128
#define BN 128

__global__ __launch_bounds__(256)
void dist_kernel(const ushort_t* __restrict__ h1, const ushort_t* __restrict__ h2,
                 const int* __restrict__ anchor1, const int* __restrict__ anchor2,
                 const float* __restrict__ S1, const float* __restrict__ S2,
                 ushort_t* __restrict__ Dmat) {
  __shared__ alignas(16) char Ah[2][8192];   // [buf][plane*2048 + row*16]
  __shared__ alignas(16) char Bh[2][8192];

  const int t = threadIdx.x;
  int bid = blockIdx.x;
  bid = (bid & 7) * 128 + (bid >> 3);   // XCD-chunked swizzle (1024 % 8 == 0)
  const int mt  = bid & 15;
  const int nt  = bid >> 4;
  const int dir = mt >> 3;
  const int i0  = (mt & 7) * BM;
  const int j0  = nt * BN;

  const ushort_t* __restrict__ Ah16 = dir ? h2 : h1;
  const ushort_t* __restrict__ Bh16 = dir ? h1 : h2;
  const float* __restrict__ SA = dir ? S2 : S1;
  const float* __restrict__ SB = dir ? S1 : S2;
  const int* __restrict__ anc  = dir ? anchor2 : anchor1;

  const int srow = t & 127;
  const int p0   = t >> 7;
  const int arow = anc[i0 + srow];
  uint32_t offA[2], offB[2];
#pragma unroll
  for (int q = 0; q < 2; ++q) {
    const int plane = p0 + 2 * q;
    offA[q] = (uint32_t)arow * DIM + plane * 8;
    offB[q] = (uint32_t)(j0 + srow) * DIM + plane * 8;
  }

  const int ty = t >> 4;
  const int tx = t & 15;

  float acc[8][8];
#pragma unroll
  for (int r = 0; r < 8; ++r)
#pragma unroll
    for (int c = 0; c < 8; ++c) acc[r][c] = 0.f;

  uint32_t ones;
  asm("v_mov_b32 %0, 0x3C003C00" : "=v"(ones));

#define STAGE(BUF, KT)                                                         \
  {                                                                            \
    _Pragma("unroll")                                                          \
    for (int q = 0; q < 2; ++q) {                                              \
      __builtin_amdgcn_global_load_lds(                                        \
          (const AS1 uint32_t*)(Ah16 + offA[q] + (KT) * 32),                   \
          (AS3 uint32_t*)(&Ah[BUF][t * 16 + q * 4096]), 16, 0, 0);             \
      __builtin_amdgcn_global_load_lds(                                        \
          (const AS1 uint32_t*)(Bh16 + offB[q] + (KT) * 32),                   \
          (AS3 uint32_t*)(&Bh[BUF][t * 16 + q * 4096]), 16, 0, 0);             \
    }                                                                          \
  }

  STAGE(0, 0)

#pragma unroll 1
  for (int kt = 0; kt < 4; ++kt) {
    __builtin_amdgcn_s_barrier();
    if (kt < 3) {
      STAGE((kt + 1) & 1, kt + 1)
      asm volatile("s_waitcnt vmcnt(4)" ::: "memory");
    } else {
      asm volatile("s_waitcnt vmcnt(0)" ::: "memory");
    }
    __builtin_amdgcn_s_barrier();
    __builtin_amdgcn_sched_barrier(0);

    const char* const Ab = &Ah[kt & 1][0] + ty * 16;
    const char* const Bb = &Bh[kt & 1][0] + tx * 16;

#pragma unroll 1
    for (int kc = 0; kc < 4; ++kc) {
      uint4 bv[8];
#pragma unroll
      for (int c = 0; c < 8; ++c)
        bv[c] = *(const uint4*)(Bb + kc * 2048 + c * 256);
      uint4 av = *(const uint4*)(Ab + kc * 2048);
#pragma unroll
      for (int r = 0; r < 8; ++r) {
        uint4 avn = av;
        if (r < 7) avn = *(const uint4*)(Ab + kc * 2048 + (r + 1) * 256);
#pragma unroll
        for (int c = 0; c < 8; ++c) {
          dot2a(acc[r][c], pkmax(av.x, bv[c].x), ones);
          dot2a(acc[r][c], pkmax(av.y, bv[c].y), ones);
          dot2a(acc[r][c], pkmax(av.z, bv[c].z), ones);
          dot2a(acc[r][c], pkmax(av.w, bv[c].w), ones);
        }
        av = avn;
      }
    }
  }

#undef STAGE

  float sa[8], sb[8];
#pragma unroll
  for (int r = 0; r < 8; ++r) sa[r] = SA[anc[i0 + r * 16 + ty]];
#pragma unroll
  for (int c = 0; c < 8; ++c) sb[c] = SB[j0 + c * 16 + tx];

#pragma unroll
  for (int r = 0; r < 8; ++r) {
    ushort_t* dst = Dmat + (size_t)(dir * NA + i0 + r * 16 + ty) * NPTS + j0 + tx;
#pragma unroll
    for (int c = 0; c < 8; ++c) {
      float d = 2.f * acc[r][c] - sa[r] - sb[c];
      dst[c * 16] = (ushort_t)pkcvt(d, 0.f);
    }
  }
}

// ---------------------------------------------------------------------------
// Kernel 2 (r15 rewrite): top-64 + hinge.
//   - keys loaded DIRECTLY global->regs (4x dwordx4, packed 2 keys/u32,
//     16 regs) — the 16KB LDS row staging was a pointless round trip.
//   - search bounds seeded with the block's exact min/max key (~10-11
//     iters on gaussian data vs fixed 15).
//   - ONE barrier per iteration via parity-indexed wred[2][4] (was 2).
//   - LDS ~1.3KB (was 17KB) -> more resident blocks hide barrier latency.
// Selection semantics identical to r14 (exact threshold + capped ties).
// ---------------------------------------------------------------------------
__global__ __launch_bounds__(256)
void select_loss_kernel(const float* __restrict__ out1, const float* __restrict__ out2,
                        const float* __restrict__ ot,
                        const int* __restrict__ anchor1, const int* __restrict__ anchor2,
                        const ushort_t* __restrict__ Dmat, float* __restrict__ partials) {
  __shared__ float a_self[DIM];
  __shared__ float terms[KSEL];
  __shared__ int   sel[KSEL];
  __shared__ unsigned wred[2][4];
  __shared__ unsigned wless[4];
  __shared__ unsigned wmin[4], wmax[4];
  __shared__ float sm_pos;
  __shared__ int sm_cnt, sm_tie;

  const int t   = threadIdx.x;
  const int b   = blockIdx.x;
  const int dir = b >> 10;
  const int i   = b & (NA - 1);

  const int a1i = anchor1[i];
  const int a2i = anchor2[i];
  const int ai_self = dir ? a2i : a1i;
  const float* __restrict__ selfB = dir ? out2 : out1;
  const float* __restrict__ othB  = dir ? out1 : out2;

  // 32 keys packed in 16 u32: u32 #(4q+m) covers u16 idx 8*(t+q*256)+2m,+1
  unsigned U[16];
  {
    const uint4* drow = (const uint4*)(Dmat + (size_t)b * NPTS);
#pragma unroll
    for (int q = 0; q < 4; ++q) {
      uint4 k = drow[t + q * 256];
      U[4 * q + 0] = k.x; U[4 * q + 1] = k.y;
      U[4 * q + 2] = k.z; U[4 * q + 3] = k.w;
    }
  }

  if (t < 32) ((float4*)a_self)[t] = ((const float4*)(selfB + (size_t)ai_self * DIM))[t];
  if (t == 0) { sm_cnt = 0; sm_tie = 0; }
  if (t < 64) {
    const float* r1 = out1 + (size_t)a1i * DIM;
    const float* r2 = out2 + (size_t)a2i * DIM;
    float pz = fabsf(r1[t] - r2[t]) + fabsf(r1[t + 64] - r2[t + 64]);
#pragma unroll
    for (int o = 32; o; o >>= 1) pz += __shfl_down(pz, o);
    if (t == 0) sm_pos = pz;
  }

  // block min/max of keys -> tight search bounds
  {
    unsigned kmin = 0xFFFFu, kmax = 0u;
#pragma unroll
    for (int u = 0; u < 16; ++u) {
      unsigned lo16 = U[u] & 0xFFFFu, hi16 = U[u] >> 16;
      kmin = min(kmin, min(lo16, hi16));
      kmax = max(kmax, max(lo16, hi16));
    }
#pragma unroll
    for (int o = 32; o; o >>= 1) {
      kmin = min(kmin, (unsigned)__shfl_xor((int)kmin, o));
      kmax = max(kmax, (unsigned)__shfl_xor((int)kmax, o));
    }
    if ((t & 63) == 0) { wmin[t >> 6] = kmin; wmax[t >> 6] = kmax; }
  }
  __syncthreads();

  unsigned lo = min(min(wmin[0], wmin[1]), min(wmin[2], wmin[3]));
  unsigned hi = max(max(wmax[0], wmax[1]), max(wmax[2], wmax[3]));

  // smallest u in [lo,hi] with count(keys <= u) >= 64; ONE barrier/iter
  int it = 0;
  while (lo < hi) {
    const unsigned mid = lo + ((hi - lo) >> 1);
    unsigned c = 0;
#pragma unroll
    for (int u = 0; u < 16; ++u) {
      c += ((U[u] & 0xFFFFu) <= mid) ? 1u : 0u;
      c += ((U[u] >> 16) <= mid) ? 1u : 0u;
    }
#pragma unroll
    for (int o = 32; o; o >>= 1) c += __shfl_down(c, o);
    if ((t & 63) == 0) wred[it & 1][t >> 6] = c;
    __syncthreads();
    c = wred[it & 1][0] + wred[it & 1][1] + wred[it & 1][2] + wred[it & 1][3];
    if (c >= 64u) hi = mid; else lo = mid + 1u;
    ++it;
  }
  const unsigned T = lo;

  {
    unsigned c = 0;
#pragma unroll
    for (int u = 0; u < 16; ++u) {
      c += ((U[u] & 0xFFFFu) < T) ? 1u : 0u;
      c += ((U[u] >> 16) < T) ? 1u : 0u;
    }
#pragma unroll
    for (int o = 32; o; o >>= 1) c += __shfl_down(c, o);
    if ((t & 63) == 0) wless[t >> 6] = c;   // separate array: no pre-barrier
  }
  __syncthreads();
  const int need = 64 - (int)(wless[0] + wless[1] + wless[2] + wless[3]);

  // collect exactly 64 indices
#pragma unroll
  for (int u = 0; u < 16; ++u) {
    const int jbase = 8 * (t + (u >> 2) * 256) + 2 * (u & 3);
#pragma unroll
    for (int h = 0; h < 2; ++h) {
      const unsigned k = h ? (U[u] >> 16) : (U[u] & 0xFFFFu);
      bool take = false;
      if (k < T) take = true;
      else if (k == T) take = (atomicAdd(&sm_tie, 1) < need);
      if (take) {
        int s = atomicAdd(&sm_cnt, 1);
        sel[s] = jbase + h;
      }
    }
  }
  __syncthreads();

  // hinge terms: 4 threads per selected negative, exact f32 recompute
  {
    const int s  = t >> 2;
    const int tq = t & 3;
    const int j  = sel[s];
    const float w = dir ? ot[(size_t)j * NPTS + ai_self]
                        : ot[(size_t)ai_self * NPTS + j];
    const float* br = othB + (size_t)j * DIM;
    float dist = 0.f;
#pragma unroll
    for (int d = 0; d < 32; d += 4) {
      float4 bv = *(const float4*)(br + tq * 32 + d);
      dist += fabsf(a_self[tq * 32 + d + 0] - w * bv.x);
      dist += fabsf(a_self[tq * 32 + d + 1] - w * bv.y);
      dist += fabsf(a_self[tq * 32 + d + 2] - w * bv.z);
      dist += fabsf(a_self[tq * 32 + d + 3] - w * bv.w);
    }
    dist += __shfl_xor(dist, 1);
    dist += __shfl_xor(dist, 2);
    if (tq == 0) terms[s] = fmaxf(0.f, sm_pos + 1.0f - dist);
  }
  __syncthreads();

  if (t < 64) {
    float v = terms[t];
#pragma unroll
    for (int o = 32; o; o >>= 1) v += __shfl_down(v, o);
    if (t == 0) partials[b] = v;
  }
}

// ---------------------------------------------------------------------------
// Kernel 3: deterministic reduction of 2048 partials, scale by 1/(A*K).
// ---------------------------------------------------------------------------
__global__ __launch_bounds__(256)
void reduce_kernel(const float* __restrict__ partials, float* __restrict__ outp) {
  __shared__ float ws4[4];
  const int t = threadIdx.x;
  float v = 0.f;
#pragma unroll
  for (int q = 0; q < 8; ++q) v += partials[t + q * 256];
#pragma unroll
  for (int o = 32; o; o >>= 1) v += __shfl_down(v, o);
  if ((t & 63) == 0) ws4[t >> 6] = v;
  __syncthreads();
  if (t == 0) outp[0] = (ws4[0] + ws4[1] + ws4[2] + ws4[3]) * (1.0f / 65536.0f);
}

extern "C" void kernel_launch(void* const* d_in, const int* in_sizes, int n_in,
                              void* d_out, int out_size, void* d_ws, size_t ws_size,
                              hipStream_t stream) {
  (void)in_sizes; (void)n_in; (void)out_size; (void)ws_size;
  const float* out1  = (const float*)d_in[0];
  const float* out2  = (const float*)d_in[1];
  const float* ot    = (const float*)d_in[2];
  const int* anchor1 = (const int*)d_in[3];
  const int* anchor2 = (const int*)d_in[4];

  // ws layout (bytes):
  //   Dmat f16 [2048][8192]            @ 0         (32 MiB)
  //   h1 f16 [8192][128]               @ 33554432  (2 MiB)
  //   h2 f16 [8192][128]               @ 35651584  (2 MiB)
  //   S1 f32 [8192]                    @ 37748736  (32 KiB)
  //   S2 f32 [8192]                    @ 37781504  (32 KiB)
  //   partials f32 [2048]              @ 37814272  (8 KiB)
  char* ws = (char*)d_ws;
  ushort_t* Dmat  = (ushort_t*)ws;
  ushort_t* h1    = (ushort_t*)(ws + 33554432);
  ushort_t* h2    = (ushort_t*)(ws + 35651584);
  float* S1       = (float*)(ws + 37748736);
  float* S2       = (float*)(ws + 37781504);
  float* partials = (float*)(ws + 37814272);

  convert_kernel<<<dim3(2048), dim3(256), 0, stream>>>(out1, out2, h1, h2, S1, S2);
  dist_kernel<<<dim3(16 * 64), dim3(256), 0, stream>>>(h1, h2, anchor1, anchor2, S1, S2, Dmat);
  select_loss_kernel<<<dim3(2 * NA), dim3(256), 0, stream>>>(out1, out2, ot, anchor1, anchor2,
                                                             Dmat, partials);
  reduce_kernel<<<dim3(1), dim3(256), 0, stream>>>(partials, (float*)d_out);
}